// Round 1
// baseline (53.355 us; speedup 1.0000x reference)
//
#include <hip/hip_runtime.h>
#include <hip/hip_bf16.h>
#include <math.h>

// ---------------------------------------------------------------------------
// RnCLoss: loss = -1/(n(n-1)) * sum_{i, k!=i} [ logits[i,k] - log(denom[i,k]) ]
//   f = row-normalized features
//   logits[i,j] = ||f_i - f_j|| / T,  T=2  -> 0.5*sqrt(max(2-2*dot, 0))
//   denom[i,k]  = sum_{j!=i, ld[i,j]>=ld[i,k]} exp(logits[i,j])
//   ld[i,j] = |labels[i]-labels[j]|
// ---------------------------------------------------------------------------

// Kernel 1: per-row inverse L2 norm of features
__global__ __launch_bounds__(256) void k_rnorm(const float* __restrict__ F,
                                               float* __restrict__ rn,
                                               int n, int d) {
    int row = blockIdx.x;
    const float* fr = F + (size_t)row * d;
    float s = 0.f;
    for (int c = threadIdx.x; c < d; c += 256) {
        float v = fr[c];
        s += v * v;
    }
    #pragma unroll
    for (int off = 32; off > 0; off >>= 1) s += __shfl_down(s, off);
    __shared__ float red[4];
    int lane = threadIdx.x & 63, wid = threadIdx.x >> 6;
    if (lane == 0) red[wid] = s;
    __syncthreads();
    if (threadIdx.x == 0) {
        float tot = red[0] + red[1] + red[2] + red[3];
        rn[row] = 1.0f / sqrtf(tot);
    }
}

// Kernel 2: G = F*F^T (scaled by rn_i*rn_j) -> logits, exp(logits)
// 32x32 tile, 256 threads, each thread 2x2 outputs, BK=32.
#define GBM 32
#define GBK 32
__global__ __launch_bounds__(256) void k_gemm(const float* __restrict__ F,
                                              const float* __restrict__ rn,
                                              float* __restrict__ logits,
                                              float* __restrict__ eexp,
                                              int n, int d) {
    __shared__ float As[GBK][GBM + 1];  // transposed: As[k][m]
    __shared__ float Bs[GBK][GBM + 1];
    int i0 = blockIdx.y * GBM;
    int j0 = blockIdx.x * GBM;
    int t = threadIdx.x;

    int lr = t >> 3;         // 0..31 : row within tile for loading
    int lc = (t & 7) << 2;   // 0,4,...,28 : k-offset (float4)
    int tr = (t >> 4) << 1;  // 0..30 : output row pair
    int tc = (t & 15) << 1;  // 0..30 : output col pair

    float acc00 = 0.f, acc01 = 0.f, acc10 = 0.f, acc11 = 0.f;

    for (int k0 = 0; k0 < d; k0 += GBK) {
        float4 a = *(const float4*)&F[(size_t)(i0 + lr) * d + k0 + lc];
        float4 b = *(const float4*)&F[(size_t)(j0 + lr) * d + k0 + lc];
        As[lc + 0][lr] = a.x; As[lc + 1][lr] = a.y;
        As[lc + 2][lr] = a.z; As[lc + 3][lr] = a.w;
        Bs[lc + 0][lr] = b.x; Bs[lc + 1][lr] = b.y;
        Bs[lc + 2][lr] = b.z; Bs[lc + 3][lr] = b.w;
        __syncthreads();
        #pragma unroll
        for (int kk = 0; kk < GBK; ++kk) {
            float a0 = As[kk][tr], a1 = As[kk][tr + 1];
            float b0 = Bs[kk][tc], b1 = Bs[kk][tc + 1];
            acc00 += a0 * b0; acc01 += a0 * b1;
            acc10 += a1 * b0; acc11 += a1 * b1;
        }
        __syncthreads();
    }

    float rni0 = rn[i0 + tr], rni1 = rn[i0 + tr + 1];
    float rnj0 = rn[j0 + tc], rnj1 = rn[j0 + tc + 1];

    float accs[2][2] = {{acc00, acc01}, {acc10, acc11}};
    float rnis[2] = {rni0, rni1};
    float rnjs[2] = {rnj0, rnj1};
    #pragma unroll
    for (int a_ = 0; a_ < 2; ++a_) {
        #pragma unroll
        for (int b_ = 0; b_ < 2; ++b_) {
            int i = i0 + tr + a_;
            int j = j0 + tc + b_;
            float g = accs[a_][b_] * rnis[a_] * rnjs[b_];
            float sq = fmaxf(2.f - 2.f * g, 0.f);
            float lg = 0.5f * sqrtf(sq);
            logits[(size_t)i * n + j] = lg;
            eexp[(size_t)i * n + j] = expf(lg);
        }
    }
}

// Kernel 3: per-row masked-denominator loss partial sums.
// One block (128 threads) per row i; each thread owns 4 k values.
__global__ __launch_bounds__(128) void k_loss(const float* __restrict__ labels,
                                              const float* __restrict__ logits,
                                              const float* __restrict__ eexp,
                                              float* __restrict__ row_sums,
                                              int n) {
    int i = blockIdx.x;
    __shared__ float2 lde[512];  // (label_diff, exp_logit) per j; e[i]=0
    __shared__ float red[2];

    float li = labels[i];
    for (int j = threadIdx.x; j < n; j += 128) {
        float e = (j == i) ? 0.f : eexp[(size_t)i * n + j];
        lde[j] = make_float2(fabsf(li - labels[j]), e);
    }
    __syncthreads();

    float ldk[4], lgk[4];
    int kidx[4];
    #pragma unroll
    for (int q = 0; q < 4; ++q) {
        int k = threadIdx.x + q * 128;
        kidx[q] = k;
        ldk[q] = lde[k].x;
        lgk[q] = logits[(size_t)i * n + k];
    }

    float s0 = 0.f, s1 = 0.f, s2 = 0.f, s3 = 0.f;
    #pragma unroll 4
    for (int j = 0; j < n; ++j) {
        float2 p = lde[j];  // broadcast read serves all 4 k's
        s0 += (p.x >= ldk[0]) ? p.y : 0.f;
        s1 += (p.x >= ldk[1]) ? p.y : 0.f;
        s2 += (p.x >= ldk[2]) ? p.y : 0.f;
        s3 += (p.x >= ldk[3]) ? p.y : 0.f;
    }
    float s[4] = {s0, s1, s2, s3};

    float acc = 0.f;
    #pragma unroll
    for (int q = 0; q < 4; ++q) {
        if (kidx[q] != i) acc += lgk[q] - logf(s[q]);
    }

    #pragma unroll
    for (int off = 32; off > 0; off >>= 1) acc += __shfl_down(acc, off);
    int lane = threadIdx.x & 63, wid = threadIdx.x >> 6;
    if (lane == 0) red[wid] = acc;
    __syncthreads();
    if (threadIdx.x == 0) row_sums[i] = red[0] + red[1];
}

// Kernel 4: final reduction over rows -> scalar loss
__global__ __launch_bounds__(256) void k_final(const float* __restrict__ row_sums,
                                               float* __restrict__ out, int n) {
    float s = 0.f;
    for (int r = threadIdx.x; r < n; r += 256) s += row_sums[r];
    #pragma unroll
    for (int off = 32; off > 0; off >>= 1) s += __shfl_down(s, off);
    __shared__ float red[4];
    int lane = threadIdx.x & 63, wid = threadIdx.x >> 6;
    if (lane == 0) red[wid] = s;
    __syncthreads();
    if (threadIdx.x == 0) {
        float tot = red[0] + red[1] + red[2] + red[3];
        out[0] = -tot / ((float)n * ((float)n - 1.0f));
    }
}

extern "C" void kernel_launch(void* const* d_in, const int* in_sizes, int n_in,
                              void* d_out, int out_size, void* d_ws, size_t ws_size,
                              hipStream_t stream) {
    const float* F      = (const float*)d_in[0];
    const float* labels = (const float*)d_in[1];
    int n = in_sizes[1];            // labels count (512)
    int d = in_sizes[0] / n;        // feature dim (512)
    float* out = (float*)d_out;

    char* ws = (char*)d_ws;
    float* rn       = (float*)ws;                       // n floats
    float* logits   = (float*)(ws + 4096);              // n*n floats
    float* eexp     = logits + (size_t)n * n;           // n*n floats
    float* row_sums = eexp + (size_t)n * n;             // n floats

    k_rnorm<<<n, 256, 0, stream>>>(F, rn, n, d);
    dim3 g(n / GBM, n / GBM);
    k_gemm<<<g, 256, 0, stream>>>(F, rn, logits, eexp, n, d);
    k_loss<<<n, 128, 0, stream>>>(labels, logits, eexp, row_sums, n);
    k_final<<<1, 256, 0, stream>>>(row_sums, out, n);
}

// Round 2
// 45.827 us; speedup vs baseline: 1.1643x; 1.1643x over previous
//
#include <hip/hip_runtime.h>
#include <hip/hip_bf16.h>
#include <math.h>

// ---------------------------------------------------------------------------
// RnCLoss: loss = -1/(n(n-1)) * sum_{i, k!=i} [ logits[i,k] - log(denom[i,k]) ]
//   logits[i,j] = ||f_i - f_j|| / T,  T=2  -> 0.5*sqrt(max(2 - 2*G_ij/sqrt(G_ii G_jj), 0))
//   denom[i,k]  = sum_{j!=i, ld[i,j]>=ld[i,k]} exp(logits[i,j])
//   ld[i,j] = |labels[i]-labels[j]|
//
// 2 kernels: (1) raw GEMM G = F F^T + diag extraction + counter reset,
//            (2) per-row fused logits/exp/masked-denominator/loss with
//                last-block grid reduction (deterministic fixed-order sum).
// ---------------------------------------------------------------------------

// Kernel 1: G = F*F^T (raw dots), diag[i] = G[i][i]. Also zeroes the
// grid-reduction counter for kernel 2 (fresh every call -> no replay state).
#define GBM 32
#define GBK 32
__global__ __launch_bounds__(256) void k_gemm(const float* __restrict__ F,
                                              float* __restrict__ G,
                                              float* __restrict__ diag,
                                              unsigned* __restrict__ counter,
                                              int n, int d) {
    if (blockIdx.x == 0 && blockIdx.y == 0 && threadIdx.x == 0) *counter = 0u;

    __shared__ float As[GBK][GBM + 1];  // transposed: As[k][m]
    __shared__ float Bs[GBK][GBM + 1];
    int i0 = blockIdx.y * GBM;
    int j0 = blockIdx.x * GBM;
    int t = threadIdx.x;

    int lr = t >> 3;         // 0..31 : row within tile for loading
    int lc = (t & 7) << 2;   // 0,4,...,28 : k-offset (float4)
    int tr = (t >> 4) << 1;  // 0..30 : output row pair
    int tc = (t & 15) << 1;  // 0..30 : output col pair

    float acc00 = 0.f, acc01 = 0.f, acc10 = 0.f, acc11 = 0.f;

    for (int k0 = 0; k0 < d; k0 += GBK) {
        float4 a = *(const float4*)&F[(size_t)(i0 + lr) * d + k0 + lc];
        float4 b = *(const float4*)&F[(size_t)(j0 + lr) * d + k0 + lc];
        As[lc + 0][lr] = a.x; As[lc + 1][lr] = a.y;
        As[lc + 2][lr] = a.z; As[lc + 3][lr] = a.w;
        Bs[lc + 0][lr] = b.x; Bs[lc + 1][lr] = b.y;
        Bs[lc + 2][lr] = b.z; Bs[lc + 3][lr] = b.w;
        __syncthreads();
        #pragma unroll
        for (int kk = 0; kk < GBK; ++kk) {
            float a0 = As[kk][tr], a1 = As[kk][tr + 1];
            float b0 = Bs[kk][tc], b1 = Bs[kk][tc + 1];
            acc00 += a0 * b0; acc01 += a0 * b1;
            acc10 += a1 * b0; acc11 += a1 * b1;
        }
        __syncthreads();
    }

    float accs[2][2] = {{acc00, acc01}, {acc10, acc11}};
    #pragma unroll
    for (int a_ = 0; a_ < 2; ++a_) {
        #pragma unroll
        for (int b_ = 0; b_ < 2; ++b_) {
            int i = i0 + tr + a_;
            int j = j0 + tc + b_;
            G[(size_t)i * n + j] = accs[a_][b_];
            if (i == j) diag[i] = accs[a_][b_];
        }
    }
}

// Kernel 2: one block (256 threads) per row i.
//   phase 1: build (label_diff, exp_logit) per j in LDS (e[i]=0)
//   phase 2: each thread owns 2 k's; masked sums via LDS broadcast
//   phase 3: block reduce -> row_sums[i]; last block does fixed-order
//            grid reduction and writes the scalar loss.
__global__ __launch_bounds__(256) void k_loss(const float* __restrict__ labels,
                                              const float* __restrict__ G,
                                              const float* __restrict__ diag,
                                              float* __restrict__ row_sums,
                                              unsigned* __restrict__ counter,
                                              float* __restrict__ out,
                                              int n) {
    int i = blockIdx.x;
    int t = threadIdx.x;
    __shared__ float2 lde[512];
    __shared__ float lab_s[512];
    __shared__ float dg_s[512];
    __shared__ float red[4];
    __shared__ int islast_s;

    for (int j = t; j < n; j += 256) {
        lab_s[j] = labels[j];
        dg_s[j]  = diag[j];
    }
    __syncthreads();

    float li = lab_s[i];
    float di = dg_s[i];
    const float* Grow = G + (size_t)i * n;

    float lgt[2], ldk[2];
    int kj[2];
    #pragma unroll
    for (int q = 0; q < 2; ++q) {
        int j = t + q * 256;
        kj[q] = j;
        float g  = Grow[j] * rsqrtf(di * dg_s[j]);
        float sq = fmaxf(2.f - 2.f * g, 0.f);
        float lg = 0.5f * sqrtf(sq);
        float e  = (j == i) ? 0.f : expf(lg);
        float ld = fabsf(li - lab_s[j]);
        lde[j] = make_float2(ld, e);
        lgt[q] = lg;
        ldk[q] = ld;
    }
    __syncthreads();

    float s0 = 0.f, s1 = 0.f;
    #pragma unroll 8
    for (int j = 0; j < n; ++j) {
        float2 p = lde[j];  // wave-uniform address -> LDS broadcast
        s0 += (p.x >= ldk[0]) ? p.y : 0.f;
        s1 += (p.x >= ldk[1]) ? p.y : 0.f;
    }

    float acc = 0.f;
    if (kj[0] != i) acc += lgt[0] - logf(s0);
    if (kj[1] != i) acc += lgt[1] - logf(s1);

    #pragma unroll
    for (int off = 32; off > 0; off >>= 1) acc += __shfl_down(acc, off);
    int lane = t & 63, wid = t >> 6;
    if (lane == 0) red[wid] = acc;
    __syncthreads();
    if (t == 0) {
        float rs = red[0] + red[1] + red[2] + red[3];
        __hip_atomic_store(&row_sums[i], rs, __ATOMIC_RELEASE,
                           __HIP_MEMORY_SCOPE_AGENT);
        unsigned prev = __hip_atomic_fetch_add(counter, 1u, __ATOMIC_ACQ_REL,
                                               __HIP_MEMORY_SCOPE_AGENT);
        islast_s = (prev == (unsigned)(gridDim.x - 1));
    }
    __syncthreads();

    if (islast_s) {
        // Fixed-order tree reduction -> deterministic output.
        float s = 0.f;
        for (int r = t; r < n; r += 256)
            s += __hip_atomic_load(&row_sums[r], __ATOMIC_ACQUIRE,
                                   __HIP_MEMORY_SCOPE_AGENT);
        #pragma unroll
        for (int off = 32; off > 0; off >>= 1) s += __shfl_down(s, off);
        if (lane == 0) red[wid] = s;
        __syncthreads();
        if (t == 0) {
            float tot = red[0] + red[1] + red[2] + red[3];
            out[0] = -tot / ((float)n * ((float)n - 1.0f));
        }
    }
}

extern "C" void kernel_launch(void* const* d_in, const int* in_sizes, int n_in,
                              void* d_out, int out_size, void* d_ws, size_t ws_size,
                              hipStream_t stream) {
    const float* F      = (const float*)d_in[0];
    const float* labels = (const float*)d_in[1];
    int n = in_sizes[1];            // labels count (512)
    int d = in_sizes[0] / n;        // feature dim (512)
    float* out = (float*)d_out;

    char* ws = (char*)d_ws;
    unsigned* counter = (unsigned*)ws;                  // 4 bytes
    float* row_sums   = (float*)(ws + 4096);            // n floats
    float* diag       = (float*)(ws + 8192);            // n floats
    float* G          = (float*)(ws + 16384);           // n*n floats

    dim3 g(n / GBM, n / GBM);
    k_gemm<<<g, 256, 0, stream>>>(F, G, diag, counter, n, d);
    k_loss<<<n, 256, 0, stream>>>(labels, G, diag, row_sums, counter, out, n);
}

// Round 3
// 40.503 us; speedup vs baseline: 1.3173x; 1.1314x over previous
//
#include <hip/hip_runtime.h>
#include <hip/hip_bf16.h>
#include <math.h>

// ---------------------------------------------------------------------------
// RnCLoss: loss = -1/(n(n-1)) * sum_{i, k!=i} [ logits[i,k] - log(denom[i,k]) ]
//   logits[i,j] = 0.5*sqrt(max(2 - 2*G_ij/sqrt(G_ii*G_jj), 0)),  G = F F^T
//   denom[i,k]  = sum_{j!=i, ld[i,j]>=ld[i,k]} exp(logits[i,j])
//   ld[i,j] = |labels[i]-labels[j]|
//
// Kernel 1: bf16-MFMA GEMM G = F F^T (raw dots) + diag + counter reset.
// Kernel 2: per-row fused logits/exp/masked-denominator/loss with
//           last-block grid reduction (deterministic fixed-order sums).
// ---------------------------------------------------------------------------

typedef __attribute__((ext_vector_type(8))) short          short8;
typedef __attribute__((ext_vector_type(8))) unsigned short ushort8;
typedef __attribute__((ext_vector_type(4))) float          f32x4;

static __device__ __forceinline__ unsigned short bf16_bits(float f) {
    __hip_bfloat16 h = __float2bfloat16(f);  // RNE
    return *reinterpret_cast<unsigned short*>(&h);
}

// Kernel 1: 64x64 tile per block, 4 waves, each wave a 32x32 quadrant
// (2x2 frags of mfma_f32_16x16x32_bf16). BK=64 (2 k-subs). fp32->bf16 in
// staging. G is symmetric so fragment row/col transposition is harmless.
__global__ __launch_bounds__(256) void k_gemm_mfma(const float* __restrict__ F,
                                                   float* __restrict__ G,
                                                   float* __restrict__ diag,
                                                   unsigned* __restrict__ counter,
                                                   int n, int d) {
    if (blockIdx.x == 0 && blockIdx.y == 0 && threadIdx.x == 0) *counter = 0u;

    __shared__ unsigned short Asm[64][72];  // 144 B row stride: 16B-aligned,
    __shared__ unsigned short Bsm[64][72];  // 2-way bank aliasing (free)

    const int t  = threadIdx.x;
    const int l  = t & 63;
    const int w  = t >> 6;
    const int wr = (w >> 1) << 5;   // wave quadrant row: 0 / 32
    const int wc = (w & 1) << 5;    // wave quadrant col: 0 / 32

    const int i0 = blockIdx.y << 6;
    const int j0 = blockIdx.x << 6;

    const int sr = t >> 2;          // staging row 0..63
    const int sc = (t & 3) << 4;    // staging col 0,16,32,48

    const int fr = l & 15;          // frag row/col within 16x16
    const int fk = (l >> 4) << 3;   // frag k base: 0,8,16,24

    f32x4 acc[2][2] = {};

    for (int k0 = 0; k0 < d; k0 += 64) {
        __syncthreads();  // previous iter's frag reads complete

        // --- stage: 16 fp32 -> 16 bf16 per thread, two 16B LDS writes ---
        const float4* pa = (const float4*)&F[(size_t)(i0 + sr) * d + k0 + sc];
        const float4* pb = (const float4*)&F[(size_t)(j0 + sr) * d + k0 + sc];
        float fa[16], fb[16];
        *(float4*)(fa + 0)  = pa[0]; *(float4*)(fa + 4)  = pa[1];
        *(float4*)(fa + 8)  = pa[2]; *(float4*)(fa + 12) = pa[3];
        *(float4*)(fb + 0)  = pb[0]; *(float4*)(fb + 4)  = pb[1];
        *(float4*)(fb + 8)  = pb[2]; *(float4*)(fb + 12) = pb[3];

        ushort8 va0, va1, vb0, vb1;
        #pragma unroll
        for (int e = 0; e < 8; ++e) {
            va0[e] = bf16_bits(fa[e]);     va1[e] = bf16_bits(fa[e + 8]);
            vb0[e] = bf16_bits(fb[e]);     vb1[e] = bf16_bits(fb[e + 8]);
        }
        *(ushort8*)&Asm[sr][sc]     = va0;
        *(ushort8*)&Asm[sr][sc + 8] = va1;
        *(ushort8*)&Bsm[sr][sc]     = vb0;
        *(ushort8*)&Bsm[sr][sc + 8] = vb1;

        __syncthreads();

        // --- compute: 2 k-subs x (2x2 frags) = 8 MFMAs ---
        #pragma unroll
        for (int ks = 0; ks < 2; ++ks) {
            short8 af0 = *(const short8*)&Asm[wr + fr     ][ks * 32 + fk];
            short8 af1 = *(const short8*)&Asm[wr + 16 + fr][ks * 32 + fk];
            short8 bf0 = *(const short8*)&Bsm[wc + fr     ][ks * 32 + fk];
            short8 bf1 = *(const short8*)&Bsm[wc + 16 + fr][ks * 32 + fk];
            acc[0][0] = __builtin_amdgcn_mfma_f32_16x16x32_bf16(af0, bf0, acc[0][0], 0, 0, 0);
            acc[0][1] = __builtin_amdgcn_mfma_f32_16x16x32_bf16(af0, bf1, acc[0][1], 0, 0, 0);
            acc[1][0] = __builtin_amdgcn_mfma_f32_16x16x32_bf16(af1, bf0, acc[1][0], 0, 0, 0);
            acc[1][1] = __builtin_amdgcn_mfma_f32_16x16x32_bf16(af1, bf1, acc[1][1], 0, 0, 0);
        }
    }

    // --- epilogue: C/D mapping col=lane&15, row=(lane>>4)*4+reg ---
    const int orow = (l >> 4) << 2;
    #pragma unroll
    for (int mi = 0; mi < 2; ++mi) {
        #pragma unroll
        for (int ni = 0; ni < 2; ++ni) {
            #pragma unroll
            for (int r = 0; r < 4; ++r) {
                int gi = i0 + wr + mi * 16 + orow + r;
                int gj = j0 + wc + ni * 16 + fr;
                float v = acc[mi][ni][r];
                G[(size_t)gi * n + gj] = v;
                if (gi == gj) diag[gi] = v;
            }
        }
    }
}

// Kernel 2: one block (256 threads) per row i.
__global__ __launch_bounds__(256) void k_loss(const float* __restrict__ labels,
                                              const float* __restrict__ G,
                                              const float* __restrict__ diag,
                                              float* __restrict__ row_sums,
                                              unsigned* __restrict__ counter,
                                              float* __restrict__ out,
                                              int n) {
    int i = blockIdx.x;
    int t = threadIdx.x;
    __shared__ float2 lde[512];
    __shared__ float lab_s[512];
    __shared__ float dg_s[512];
    __shared__ float red[4];
    __shared__ int islast_s;

    for (int j = t; j < n; j += 256) {
        lab_s[j] = labels[j];
        dg_s[j]  = diag[j];
    }
    __syncthreads();

    float li = lab_s[i];
    float di = dg_s[i];
    const float* Grow = G + (size_t)i * n;

    float lgt[2], ldk[2];
    int kj[2];
    #pragma unroll
    for (int q = 0; q < 2; ++q) {
        int j = t + q * 256;
        kj[q] = j;
        float g  = Grow[j] * rsqrtf(di * dg_s[j]);
        float sq = fmaxf(2.f - 2.f * g, 0.f);
        float lg = 0.5f * sqrtf(sq);
        float e  = (j == i) ? 0.f : expf(lg);
        float ld = fabsf(li - lab_s[j]);
        lde[j] = make_float2(ld, e);
        lgt[q] = lg;
        ldk[q] = ld;
    }
    __syncthreads();

    float s0 = 0.f, s1 = 0.f;
    #pragma unroll 8
    for (int j = 0; j < n; ++j) {
        float2 p = lde[j];  // wave-uniform address -> LDS broadcast
        s0 += (p.x >= ldk[0]) ? p.y : 0.f;
        s1 += (p.x >= ldk[1]) ? p.y : 0.f;
    }

    float acc = 0.f;
    if (kj[0] != i) acc += lgt[0] - logf(s0);
    if (kj[1] != i) acc += lgt[1] - logf(s1);

    #pragma unroll
    for (int off = 32; off > 0; off >>= 1) acc += __shfl_down(acc, off);
    int lane = t & 63, wid = t >> 6;
    if (lane == 0) red[wid] = acc;
    __syncthreads();
    if (t == 0) {
        float rs = red[0] + red[1] + red[2] + red[3];
        __hip_atomic_store(&row_sums[i], rs, __ATOMIC_RELEASE,
                           __HIP_MEMORY_SCOPE_AGENT);
        unsigned prev = __hip_atomic_fetch_add(counter, 1u, __ATOMIC_ACQ_REL,
                                               __HIP_MEMORY_SCOPE_AGENT);
        islast_s = (prev == (unsigned)(gridDim.x - 1));
    }
    __syncthreads();

    if (islast_s) {
        float s = 0.f;
        for (int r = t; r < n; r += 256)
            s += __hip_atomic_load(&row_sums[r], __ATOMIC_ACQUIRE,
                                   __HIP_MEMORY_SCOPE_AGENT);
        #pragma unroll
        for (int off = 32; off > 0; off >>= 1) s += __shfl_down(s, off);
        if (lane == 0) red[wid] = s;
        __syncthreads();
        if (t == 0) {
            float tot = red[0] + red[1] + red[2] + red[3];
            out[0] = -tot / ((float)n * ((float)n - 1.0f));
        }
    }
}

extern "C" void kernel_launch(void* const* d_in, const int* in_sizes, int n_in,
                              void* d_out, int out_size, void* d_ws, size_t ws_size,
                              hipStream_t stream) {
    const float* F      = (const float*)d_in[0];
    const float* labels = (const float*)d_in[1];
    int n = in_sizes[1];            // 512
    int d = in_sizes[0] / n;        // 512
    float* out = (float*)d_out;

    char* ws = (char*)d_ws;
    unsigned* counter = (unsigned*)ws;                  // 4 bytes
    float* row_sums   = (float*)(ws + 4096);            // n floats
    float* diag       = (float*)(ws + 8192);            // n floats
    float* G          = (float*)(ws + 16384);           // n*n floats

    dim3 g(n / 64, n / 64);
    k_gemm_mfma<<<g, 256, 0, stream>>>(F, G, diag, counter, n, d);
    k_loss<<<n, 256, 0, stream>>>(labels, G, diag, row_sums, counter, out, n);
}